// Round 1
// baseline (375.010 us; speedup 1.0000x reference)
//
#include <hip/hip_runtime.h>
#include <hip/hip_bf16.h>

#define NN 4096
#define FD 128
#define NDIM 2
#define CAP 256

// ---------- workspace layout (float offsets) ----------
// hmat  [2][4][4096][128] : p=0 X@Wp, 1 X@Ws, 2 X@Wu, 3 X@Wd
// svec  [2][4][4096]      : v=0 s1u, 1 s2u, 2 s1d, 3 s2d
// hp    [2][4][4096][128] : split-K partials of L@h0
// gu,gd [2][4096][128]
#define OFF_HMAT 0
#define OFF_SVEC 4194304
#define OFF_HP   4227072
#define OFF_GU   8421376
#define OFF_GD   9469952

__device__ __forceinline__ float f4get(const float4& v, int j) {
    return j == 0 ? v.x : j == 1 ? v.y : j == 2 ? v.z : v.w;
}

// ---------------- K1: hmat[d][p] = X[d] @ W_p[d] ----------------
__global__ __launch_bounds__(256) void k_xw(
    const float* __restrict__ X, const float* __restrict__ Wp,
    const float* __restrict__ Wsm, const float* __restrict__ Wu,
    const float* __restrict__ Wd, float* __restrict__ hmat) {
  int d = blockIdx.z, p = blockIdx.y;
  int r0 = blockIdx.x * 32;
  const float* W = (p == 0 ? Wp : p == 1 ? Wsm : p == 2 ? Wu : Wd) + (size_t)d * FD * FD;
  const float* Xd = X + ((size_t)d * NN + r0) * FD;
  __shared__ float Xs[32][36];
  __shared__ float Wt[32][FD];
  int t = threadIdx.x;
  int c0 = (t & 31) * 4, rt = (t >> 5) * 4;
  float acc[4][4] = {};
  for (int kk = 0; kk < FD; kk += 32) {
    {
      int r = t >> 3, c4 = (t & 7) * 4;
      *(float4*)&Xs[r][c4] = *(const float4*)(Xd + (size_t)r * FD + kk + c4);
    }
    {
      const float4* src = (const float4*)(W + (size_t)kk * FD);
      float4* dst = (float4*)&Wt[0][0];
#pragma unroll
      for (int u = 0; u < 4; u++) dst[t + u * 256] = src[t + u * 256];
    }
    __syncthreads();
#pragma unroll
    for (int k4 = 0; k4 < 32; k4 += 4) {
      float4 a0 = *(const float4*)&Xs[rt + 0][k4];
      float4 a1 = *(const float4*)&Xs[rt + 1][k4];
      float4 a2 = *(const float4*)&Xs[rt + 2][k4];
      float4 a3 = *(const float4*)&Xs[rt + 3][k4];
#pragma unroll
      for (int j = 0; j < 4; j++) {
        float4 b = *(const float4*)&Wt[k4 + j][c0];
        float v0 = f4get(a0, j), v1 = f4get(a1, j), v2 = f4get(a2, j), v3 = f4get(a3, j);
        acc[0][0] += v0 * b.x; acc[0][1] += v0 * b.y; acc[0][2] += v0 * b.z; acc[0][3] += v0 * b.w;
        acc[1][0] += v1 * b.x; acc[1][1] += v1 * b.y; acc[1][2] += v1 * b.z; acc[1][3] += v1 * b.w;
        acc[2][0] += v2 * b.x; acc[2][1] += v2 * b.y; acc[2][2] += v2 * b.z; acc[2][3] += v2 * b.w;
        acc[3][0] += v3 * b.x; acc[3][1] += v3 * b.y; acc[3][2] += v3 * b.z; acc[3][3] += v3 * b.w;
      }
    }
    __syncthreads();
  }
  float* o = hmat + (((size_t)(d * 4 + p)) * NN + r0) * FD;
#pragma unroll
  for (int r = 0; r < 4; r++) {
    float4 v = make_float4(acc[r][0], acc[r][1], acc[r][2], acc[r][3]);
    *(float4*)(o + (size_t)(rt + r) * FD + c0) = v;
  }
}

// ---------------- K1b: svec = h @ a ----------------
__global__ __launch_bounds__(256) void k_svec(
    const float* __restrict__ hmat, const float* __restrict__ au1,
    const float* __restrict__ au2, const float* __restrict__ ad1,
    const float* __restrict__ ad2, float* __restrict__ svec) {
  int v = blockIdx.y, d = blockIdx.z;
  int w = threadIdx.x >> 6, lane = threadIdx.x & 63;
  int i = blockIdx.x * 4 + w;
  const float* a = (v == 0 ? au1 : v == 1 ? au2 : v == 2 ? ad1 : ad2) + (size_t)d * FD;
  int p = 2 + (v >> 1);
  const float* h = hmat + ((size_t)(d * 4 + p) * NN + i) * FD;
  float x = h[lane] * a[lane] + h[64 + lane] * a[64 + lane];
#pragma unroll
  for (int o = 1; o < 64; o <<= 1) x += __shfl_xor(x, o);
  if (lane == 0) svec[(size_t)(d * 4 + v) * NN + i] = x;
}

// ---------------- K2: hp[d][s] = L[d][:, slice] @ h0[d][slice, :] ----------------
__global__ __launch_bounds__(256) void k_lgemm(
    const float* __restrict__ L, const float* __restrict__ hmat,
    float* __restrict__ hp) {
  int d = blockIdx.z, ks = blockIdx.y;
  int r0 = blockIdx.x * 128;
  const float* Lr = L + (size_t)d * NN * NN;
  const float* B = hmat + (size_t)(d * 4 + 0) * NN * FD;  // h0
  float* out = hp + ((size_t)(d * 4 + ks) * NN + r0) * FD;

  __shared__ float As[128][36];
  __shared__ float Bs[32][FD];
  int t = threadIdx.x;
  int c0 = (t & 15) * 8;
  int r0t = (t >> 4) * 8;
  float acc[8][8] = {};
  int kbeg = ks * 1024;
  for (int kk = kbeg; kk < kbeg + 1024; kk += 32) {
    // stage A tile 128x32 (1024 float4, 4 per thread)
#pragma unroll
    for (int u = 0; u < 4; u++) {
      int id = t + u * 256;
      int r = id >> 3, c4 = (id & 7) * 4;
      *(float4*)&As[r][c4] = *(const float4*)(Lr + (size_t)(r0 + r) * NN + kk + c4);
    }
    // stage B tile 32x128 (contiguous 16 KB)
    {
      const float4* src = (const float4*)(B + (size_t)kk * FD);
      float4* dst = (float4*)&Bs[0][0];
#pragma unroll
      for (int u = 0; u < 4; u++) dst[t + u * 256] = src[t + u * 256];
    }
    __syncthreads();
#pragma unroll
    for (int k4 = 0; k4 < 32; k4 += 4) {
      float4 af[8];
#pragma unroll
      for (int r = 0; r < 8; r++) af[r] = *(const float4*)&As[r0t + r][k4];
#pragma unroll
      for (int j = 0; j < 4; j++) {
        float4 b0 = *(const float4*)&Bs[k4 + j][c0];
        float4 b1 = *(const float4*)&Bs[k4 + j][c0 + 4];
#pragma unroll
        for (int r = 0; r < 8; r++) {
          float a = f4get(af[r], j);
          acc[r][0] += a * b0.x; acc[r][1] += a * b0.y; acc[r][2] += a * b0.z; acc[r][3] += a * b0.w;
          acc[r][4] += a * b1.x; acc[r][5] += a * b1.y; acc[r][6] += a * b1.z; acc[r][7] += a * b1.w;
        }
      }
    }
    __syncthreads();
  }
#pragma unroll
  for (int r = 0; r < 8; r++) {
    float4 v0 = make_float4(acc[r][0], acc[r][1], acc[r][2], acc[r][3]);
    float4 v1 = make_float4(acc[r][4], acc[r][5], acc[r][6], acc[r][7]);
    *(float4*)(out + (size_t)(r0t + r) * FD + c0) = v0;
    *(float4*)(out + (size_t)(r0t + r) * FD + c0 + 4) = v1;
  }
}

// ---------------- K3: GAT (sparse softmax over 0/1 adjacency) ----------------
__global__ __launch_bounds__(256) void k_gat(
    const float* __restrict__ Lu, const float* __restrict__ Ldn,
    const float* __restrict__ hmat, const float* __restrict__ svec,
    float* __restrict__ gu, float* __restrict__ gd) {
  int d = blockIdx.z, a = blockIdx.y;
  int w = threadIdx.x >> 6, lane = threadIdx.x & 63;
  int i = blockIdx.x * 4 + w;
  const float* Arow = (a ? Ldn : Lu) + ((size_t)d * NN + i) * (size_t)NN;
  const float* h = hmat + (size_t)(d * 4 + 2 + a) * NN * FD;
  const float* s1 = svec + (size_t)(d * 4 + 2 * a) * NN;
  const float* s2 = svec + (size_t)(d * 4 + 2 * a + 1) * NN;
  float* g = (a ? gd : gu) + ((size_t)d * NN + i) * FD;

  __shared__ int ej[4][CAP];
  __shared__ float wt[4][CAP];
  int cnt = 0;
  for (int base = 0; base < NN; base += 256) {
    float4 v = *(const float4*)(Arow + base + lane * 4);
#pragma unroll
    for (int q = 0; q < 4; q++) {
      float vv = f4get(v, q);
      unsigned long long m = __ballot(vv == 1.0f);
      if (m) {
        if (vv == 1.0f) {
          int pos = cnt + __popcll(m & ((1ull << lane) - 1ull));
          if (pos < CAP) ej[w][pos] = base + lane * 4 + q;
        }
        cnt += __popcll(m);
      }
    }
  }
  cnt = min(cnt, CAP);
  float s1i = s1[i];
  float mx = -1e30f;
  for (int e0 = 0; e0 < cnt; e0 += 64) {
    int e = e0 + lane;
    float sc = -1e30f;
    if (e < cnt) {
      int j = ej[w][e];
      float x = s1i + s2[j];
      sc = x > 0.0f ? x : 0.01f * x;
      wt[w][e] = sc;
    }
    mx = fmaxf(mx, sc);
  }
#pragma unroll
  for (int o = 1; o < 64; o <<= 1) mx = fmaxf(mx, __shfl_xor(mx, o));
  float sum = 0.0f;
  for (int e0 = 0; e0 < cnt; e0 += 64) {
    int e = e0 + lane;
    float pv = 0.0f;
    if (e < cnt) {
      pv = expf(wt[w][e] - mx);
      wt[w][e] = pv;
    }
    sum += pv;
  }
#pragma unroll
  for (int o = 1; o < 64; o <<= 1) sum += __shfl_xor(sum, o);
  float inv = (cnt > 0) ? 1.0f / sum : 0.0f;
  float acc0 = 0.0f, acc1 = 0.0f;
  for (int e = 0; e < cnt; e++) {
    float wg = wt[w][e] * inv;
    const float* hr = h + (size_t)ej[w][e] * FD;
    acc0 += wg * hr[lane];
    acc1 += wg * hr[64 + lane];
  }
  g[lane] = acc0;
  g[64 + lane] = acc1;
}

// ---------------- K4: combine with tanh ----------------
__global__ __launch_bounds__(256) void k_combine(
    const float* __restrict__ hmat, const float* __restrict__ hp,
    const float* __restrict__ gu, const float* __restrict__ gd,
    float* __restrict__ out) {
  const size_t tot4 = (size_t)NDIM * NN * FD / 4;
  for (size_t i4 = (size_t)blockIdx.x * blockDim.x + threadIdx.x; i4 < tot4;
       i4 += (size_t)gridDim.x * blockDim.x) {
    size_t i = i4 * 4;
    int d = (int)(i >> 19);          // N*FD = 524288 = 2^19
    size_t rem = i & 524287;
    float4 hs = *(const float4*)(hmat + ((size_t)(d * 4 + 1) << 19) + rem);
    float4 p0 = *(const float4*)(hp + ((size_t)(d * 4 + 0) << 19) + rem);
    float4 p1 = *(const float4*)(hp + ((size_t)(d * 4 + 1) << 19) + rem);
    float4 p2 = *(const float4*)(hp + ((size_t)(d * 4 + 2) << 19) + rem);
    float4 p3 = *(const float4*)(hp + ((size_t)(d * 4 + 3) << 19) + rem);
    float4 u = *(const float4*)(gu + ((size_t)d << 19) + rem);
    float4 dd = *(const float4*)(gd + ((size_t)d << 19) + rem);
    float4 o;
    o.x = tanhf(hs.x) + tanhf(u.x) + tanhf(dd.x) + tanhf(p0.x + p1.x + p2.x + p3.x);
    o.y = tanhf(hs.y) + tanhf(u.y) + tanhf(dd.y) + tanhf(p0.y + p1.y + p2.y + p3.y);
    o.z = tanhf(hs.z) + tanhf(u.z) + tanhf(dd.z) + tanhf(p0.z + p1.z + p2.z + p3.z);
    o.w = tanhf(hs.w) + tanhf(u.w) + tanhf(dd.w) + tanhf(p0.w + p1.w + p2.w + p3.w);
    *(float4*)(out + i) = o;
  }
}

extern "C" void kernel_launch(void* const* d_in, const int* in_sizes, int n_in,
                              void* d_out, int out_size, void* d_ws, size_t ws_size,
                              hipStream_t stream) {
  const float* X   = (const float*)d_in[0];
  const float* L   = (const float*)d_in[1];
  const float* Lu  = (const float*)d_in[2];
  const float* Ldn = (const float*)d_in[3];
  const float* Wp  = (const float*)d_in[4];
  const float* Wsm = (const float*)d_in[5];
  const float* Wu  = (const float*)d_in[6];
  const float* au1 = (const float*)d_in[7];
  const float* au2 = (const float*)d_in[8];
  const float* Wd  = (const float*)d_in[9];
  const float* ad1 = (const float*)d_in[10];
  const float* ad2 = (const float*)d_in[11];
  float* out = (float*)d_out;
  float* ws = (float*)d_ws;

  float* hmat = ws + OFF_HMAT;
  float* svec = ws + OFF_SVEC;
  float* hp   = ws + OFF_HP;
  float* gu   = ws + OFF_GU;
  float* gd   = ws + OFF_GD;

  k_xw<<<dim3(NN / 32, 4, NDIM), 256, 0, stream>>>(X, Wp, Wsm, Wu, Wd, hmat);
  k_svec<<<dim3(NN / 4, 4, NDIM), 256, 0, stream>>>(hmat, au1, au2, ad1, ad2, svec);
  k_lgemm<<<dim3(NN / 128, 4, NDIM), 256, 0, stream>>>(L, hmat, hp);
  k_gat<<<dim3(NN / 4, 2, NDIM), 256, 0, stream>>>(Lu, Ldn, hmat, svec, gu, gd);
  k_combine<<<1024, 256, 0, stream>>>(hmat, hp, gu, gd, out);
}

// Round 2
// 136.319 us; speedup vs baseline: 2.7510x; 2.7510x over previous
//
#include <hip/hip_runtime.h>
#include <hip/hip_bf16.h>

#define NN 4096
#define FD 128
#define NDIM 2
#define CAP 256

// ---------- workspace layout (float offsets) ----------
// hmat [2][3][4096][128] fp32 : q=0 X@Ws (h_s), q=1 X@Wu, q=2 X@Wd
// svec [2][4][4096]           : v=0 s1u, 1 s2u, 2 s1d, 3 s2d
// hp   [2][4][4096][128] fp32 : split-K partials of L@h0
// gu,gd [2][4096][128]
// h0T  [2][128][4096] f16     : (X@Wp) transposed, f16 (B operand of L-GEMM)
#define OFF_HMAT 0
#define OFF_SVEC 3145728
#define OFF_HP   3178496
#define OFF_GU   7372800
#define OFF_GD   8421376
#define OFF_H0T  9469952

typedef _Float16 f16x8 __attribute__((ext_vector_type(8)));
typedef float f32x4 __attribute__((ext_vector_type(4)));

union P4 { _Float16 h[4]; int2 i2; };

__device__ __forceinline__ float f4get(const float4& v, int j) {
    return j == 0 ? v.x : j == 1 ? v.y : j == 2 ? v.z : v.w;
}

// ---------------- K1: MFMA f16 GEMM  h = X @ W_p, tile 128x128, K=128 ----------------
// p==0 -> store h0T f16 (transposed); p>0 -> store hmat fp32 slot p-1
__global__ __launch_bounds__(256) void k_xw(
    const float* __restrict__ X, const float* __restrict__ Wp,
    const float* __restrict__ Wsm, const float* __restrict__ Wu,
    const float* __restrict__ Wd, float* __restrict__ hmat,
    _Float16* __restrict__ h0T) {
  int d = blockIdx.z, p = blockIdx.y;
  int r0 = blockIdx.x * 128;
  const float* W = (p == 0 ? Wp : p == 1 ? Wsm : p == 2 ? Wu : Wd) + (size_t)d * FD * FD;
  const float* Xd = X + ((size_t)d * NN + r0) * FD;
  __shared__ int4 As4[2048];  // 32 KB: A[128 rows][128 k] f16, XOR-swizzled
  __shared__ int4 Bs4[2048];  // 32 KB: Bt[128 n][128 k] f16, XOR-swizzled
  char* As = (char*)As4; char* Bs = (char*)Bs4;
  int t = threadIdx.x;

  // stage A: X tile 128x128 fp32 -> f16, 16 float4 per thread
#pragma unroll 4
  for (int u = 0; u < 16; u++) {
    int id = t + u * 256;
    int row = id >> 5, k4 = (id & 31) * 4;
    float4 v = *(const float4*)(Xd + (size_t)row * FD + k4);
    P4 pk;
    pk.h[0] = (_Float16)v.x; pk.h[1] = (_Float16)v.y;
    pk.h[2] = (_Float16)v.z; pk.h[3] = (_Float16)v.w;
    int off = (row * 256 + k4 * 2) ^ ((row & 7) << 4);
    *(int2*)(As + off) = pk.i2;
  }
  // stage B: W [k][n] fp32 -> Bt[n][k] f16 (transpose via scalar b16 writes)
#pragma unroll 4
  for (int u = 0; u < 16; u++) {
    int id = t + u * 256;
    int k = id >> 5, n4 = (id & 31) * 4;
    float4 v = *(const float4*)(W + (size_t)k * FD + n4);
#pragma unroll
    for (int j = 0; j < 4; j++) {
      int n = n4 + j;
      int off = (n * 256 + k * 2) ^ ((n & 7) << 4);
      *(_Float16*)(Bs + off) = (_Float16)f4get(v, j);
    }
  }
  __syncthreads();

  int w = t >> 6, l = t & 63;
  int lr = l & 15, lkb = (l >> 4) * 16;  // byte offset of this lane's k-slice
  f32x4 acc[2][8] = {};
#pragma unroll
  for (int kb = 0; kb < 4; kb++) {
    f16x8 a[2], b[8];
#pragma unroll
    for (int m = 0; m < 2; m++) {
      int row = w * 32 + m * 16 + lr;
      int off = (row * 256 + kb * 64 + lkb) ^ ((row & 7) << 4);
      a[m] = *(const f16x8*)(As + off);
    }
#pragma unroll
    for (int n = 0; n < 8; n++) {
      int rn = n * 16 + lr;
      int off = (rn * 256 + kb * 64 + lkb) ^ ((rn & 7) << 4);
      b[n] = *(const f16x8*)(Bs + off);
    }
#pragma unroll
    for (int m = 0; m < 2; m++)
#pragma unroll
      for (int n = 0; n < 8; n++)
        acc[m][n] = __builtin_amdgcn_mfma_f32_16x16x32_f16(a[m], b[n], acc[m][n], 0, 0, 0);
  }

  // D layout: col = lane&15, row = (lane>>4)*4 + reg
  if (p == 0) {
    _Float16* hT = h0T + (size_t)d * FD * NN;
#pragma unroll
    for (int m = 0; m < 2; m++)
#pragma unroll
      for (int n = 0; n < 8; n++) {
        int col = n * 16 + lr;
        int grow = r0 + w * 32 + m * 16 + (l >> 4) * 4;
        P4 pk;
#pragma unroll
        for (int r = 0; r < 4; r++) pk.h[r] = (_Float16)acc[m][n][r];
        *(int2*)(hT + (size_t)col * NN + grow) = pk.i2;
      }
  } else {
    float* o = hmat + ((size_t)(d * 3 + p - 1) * NN + r0) * FD;
#pragma unroll
    for (int m = 0; m < 2; m++)
#pragma unroll
      for (int n = 0; n < 8; n++)
#pragma unroll
        for (int r = 0; r < 4; r++)
          o[(size_t)(w * 32 + m * 16 + (l >> 4) * 4 + r) * FD + n * 16 + lr] = acc[m][n][r];
  }
}

// ---------------- K1b: svec = h @ a ----------------
__global__ __launch_bounds__(256) void k_svec(
    const float* __restrict__ hmat, const float* __restrict__ au1,
    const float* __restrict__ au2, const float* __restrict__ ad1,
    const float* __restrict__ ad2, float* __restrict__ svec) {
  int v = blockIdx.y, d = blockIdx.z;
  int w = threadIdx.x >> 6, lane = threadIdx.x & 63;
  int i = blockIdx.x * 4 + w;
  const float* a = (v == 0 ? au1 : v == 1 ? au2 : v == 2 ? ad1 : ad2) + (size_t)d * FD;
  const float* h = hmat + ((size_t)(d * 3 + 1 + (v >> 1)) * NN + i) * FD;
  float x = h[lane] * a[lane] + h[64 + lane] * a[64 + lane];
#pragma unroll
  for (int o = 1; o < 64; o <<= 1) x += __shfl_xor(x, o);
  if (lane == 0) svec[(size_t)(d * 4 + v) * NN + i] = x;
}

// ---------------- K2: MFMA f16 GEMM  hp[d][ks] = L[d][:,slice] @ h0[slice,:] ----------------
__global__ __launch_bounds__(256) void k_lgemm(
    const float* __restrict__ L, const _Float16* __restrict__ h0T,
    float* __restrict__ hp) {
  int d = blockIdx.z, ks = blockIdx.y;
  int r0 = blockIdx.x * 128;
  const float* Lr = L + (size_t)d * NN * NN;
  const _Float16* hT = h0T + (size_t)d * FD * NN;
  __shared__ int4 As4[1024];  // 16 KB: A[128 rows][64 k] f16, XOR-swizzled
  __shared__ int4 Bs4[1024];  // 16 KB: Bt[128 n][64 k] f16, XOR-swizzled
  char* As = (char*)As4; char* Bs = (char*)Bs4;
  int t = threadIdx.x;
  int w = t >> 6, l = t & 63;
  int lr = l & 15, lkb = (l >> 4) * 16;
  f32x4 acc[2][8] = {};
  int kbeg = ks * 1024;
  for (int kk = kbeg; kk < kbeg + 1024; kk += 64) {
    // stage A: L tile 128x64 fp32 -> f16 (8 float4/thread)
#pragma unroll
    for (int u = 0; u < 8; u++) {
      int id = t + u * 256;
      int row = id >> 4, k4 = (id & 15) * 4;
      float4 v = *(const float4*)(Lr + (size_t)(r0 + row) * NN + kk + k4);
      P4 pk;
      pk.h[0] = (_Float16)v.x; pk.h[1] = (_Float16)v.y;
      pk.h[2] = (_Float16)v.z; pk.h[3] = (_Float16)v.w;
      int off = (row * 128 + k4 * 2) ^ ((row & 7) << 4);
      *(int2*)(As + off) = pk.i2;
    }
    // stage B: h0T [n][k] f16, 4 x 16B per thread
#pragma unroll
    for (int u = 0; u < 4; u++) {
      int id = t + u * 256;
      int n = id >> 3, k8 = (id & 7) * 8;
      int4 v = *(const int4*)(hT + (size_t)n * NN + kk + k8);
      int off = (n * 128 + k8 * 2) ^ ((n & 7) << 4);
      *(int4*)(Bs + off) = v;
    }
    __syncthreads();
#pragma unroll
    for (int kb = 0; kb < 2; kb++) {
      f16x8 a[2], b[8];
#pragma unroll
      for (int m = 0; m < 2; m++) {
        int row = w * 32 + m * 16 + lr;
        int off = (row * 128 + kb * 64 + lkb) ^ ((row & 7) << 4);
        a[m] = *(const f16x8*)(As + off);
      }
#pragma unroll
      for (int n = 0; n < 8; n++) {
        int rn = n * 16 + lr;
        int off = (rn * 128 + kb * 64 + lkb) ^ ((rn & 7) << 4);
        b[n] = *(const f16x8*)(Bs + off);
      }
#pragma unroll
      for (int m = 0; m < 2; m++)
#pragma unroll
        for (int n = 0; n < 8; n++)
          acc[m][n] = __builtin_amdgcn_mfma_f32_16x16x32_f16(a[m], b[n], acc[m][n], 0, 0, 0);
    }
    __syncthreads();
  }
  float* o = hp + ((size_t)(d * 4 + ks) * NN + r0) * FD;
#pragma unroll
  for (int m = 0; m < 2; m++)
#pragma unroll
    for (int n = 0; n < 8; n++)
#pragma unroll
      for (int r = 0; r < 4; r++)
        o[(size_t)(w * 32 + m * 16 + (l >> 4) * 4 + r) * FD + n * 16 + lr] = acc[m][n][r];
}

// ---------------- K3: GAT (sparse softmax over 0/1 adjacency) ----------------
__global__ __launch_bounds__(256) void k_gat(
    const float* __restrict__ Lu, const float* __restrict__ Ldn,
    const float* __restrict__ hmat, const float* __restrict__ svec,
    float* __restrict__ gu, float* __restrict__ gd) {
  int d = blockIdx.z, a = blockIdx.y;
  int w = threadIdx.x >> 6, lane = threadIdx.x & 63;
  int i = blockIdx.x * 4 + w;
  const float* Arow = (a ? Ldn : Lu) + ((size_t)d * NN + i) * (size_t)NN;
  const float* h = hmat + (size_t)(d * 3 + 1 + a) * NN * FD;
  const float* s1 = svec + (size_t)(d * 4 + 2 * a) * NN;
  const float* s2 = svec + (size_t)(d * 4 + 2 * a + 1) * NN;
  float* g = (a ? gd : gu) + ((size_t)d * NN + i) * FD;

  __shared__ int ej[4][CAP];
  __shared__ float wt[4][CAP];
  int cnt = 0;
  for (int base = 0; base < NN; base += 256) {
    float4 v = *(const float4*)(Arow + base + lane * 4);
#pragma unroll
    for (int q = 0; q < 4; q++) {
      float vv = f4get(v, q);
      unsigned long long m = __ballot(vv == 1.0f);
      if (m) {
        if (vv == 1.0f) {
          int pos = cnt + __popcll(m & ((1ull << lane) - 1ull));
          if (pos < CAP) ej[w][pos] = base + lane * 4 + q;
        }
        cnt += __popcll(m);
      }
    }
  }
  cnt = min(cnt, CAP);
  float s1i = s1[i];
  float mx = -1e30f;
  for (int e0 = 0; e0 < cnt; e0 += 64) {
    int e = e0 + lane;
    float sc = -1e30f;
    if (e < cnt) {
      int j = ej[w][e];
      float x = s1i + s2[j];
      sc = x > 0.0f ? x : 0.01f * x;
      wt[w][e] = sc;
    }
    mx = fmaxf(mx, sc);
  }
#pragma unroll
  for (int o = 1; o < 64; o <<= 1) mx = fmaxf(mx, __shfl_xor(mx, o));
  float sum = 0.0f;
  for (int e0 = 0; e0 < cnt; e0 += 64) {
    int e = e0 + lane;
    float pv = 0.0f;
    if (e < cnt) {
      pv = expf(wt[w][e] - mx);
      wt[w][e] = pv;
    }
    sum += pv;
  }
#pragma unroll
  for (int o = 1; o < 64; o <<= 1) sum += __shfl_xor(sum, o);
  float inv = (cnt > 0) ? 1.0f / sum : 0.0f;
  float acc0 = 0.0f, acc1 = 0.0f;
  for (int e = 0; e < cnt; e++) {
    float wg = wt[w][e] * inv;
    const float* hr = h + (size_t)ej[w][e] * FD;
    acc0 += wg * hr[lane];
    acc1 += wg * hr[64 + lane];
  }
  g[lane] = acc0;
  g[64 + lane] = acc1;
}

// ---------------- K4: combine with tanh ----------------
__global__ __launch_bounds__(256) void k_combine(
    const float* __restrict__ hmat, const float* __restrict__ hp,
    const float* __restrict__ gu, const float* __restrict__ gd,
    float* __restrict__ out) {
  const size_t tot4 = (size_t)NDIM * NN * FD / 4;
  for (size_t i4 = (size_t)blockIdx.x * blockDim.x + threadIdx.x; i4 < tot4;
       i4 += (size_t)gridDim.x * blockDim.x) {
    size_t i = i4 * 4;
    int d = (int)(i >> 19);          // N*FD = 524288 = 2^19
    size_t rem = i & 524287;
    float4 hs = *(const float4*)(hmat + ((size_t)(d * 3) << 19) + rem);
    float4 p0 = *(const float4*)(hp + ((size_t)(d * 4 + 0) << 19) + rem);
    float4 p1 = *(const float4*)(hp + ((size_t)(d * 4 + 1) << 19) + rem);
    float4 p2 = *(const float4*)(hp + ((size_t)(d * 4 + 2) << 19) + rem);
    float4 p3 = *(const float4*)(hp + ((size_t)(d * 4 + 3) << 19) + rem);
    float4 u = *(const float4*)(gu + ((size_t)d << 19) + rem);
    float4 dd = *(const float4*)(gd + ((size_t)d << 19) + rem);
    float4 o;
    o.x = tanhf(hs.x) + tanhf(u.x) + tanhf(dd.x) + tanhf(p0.x + p1.x + p2.x + p3.x);
    o.y = tanhf(hs.y) + tanhf(u.y) + tanhf(dd.y) + tanhf(p0.y + p1.y + p2.y + p3.y);
    o.z = tanhf(hs.z) + tanhf(u.z) + tanhf(dd.z) + tanhf(p0.z + p1.z + p2.z + p3.z);
    o.w = tanhf(hs.w) + tanhf(u.w) + tanhf(dd.w) + tanhf(p0.w + p1.w + p2.w + p3.w);
    *(float4*)(out + i) = o;
  }
}

extern "C" void kernel_launch(void* const* d_in, const int* in_sizes, int n_in,
                              void* d_out, int out_size, void* d_ws, size_t ws_size,
                              hipStream_t stream) {
  const float* X   = (const float*)d_in[0];
  const float* L   = (const float*)d_in[1];
  const float* Lu  = (const float*)d_in[2];
  const float* Ldn = (const float*)d_in[3];
  const float* Wp  = (const float*)d_in[4];
  const float* Wsm = (const float*)d_in[5];
  const float* Wu  = (const float*)d_in[6];
  const float* au1 = (const float*)d_in[7];
  const float* au2 = (const float*)d_in[8];
  const float* Wd  = (const float*)d_in[9];
  const float* ad1 = (const float*)d_in[10];
  const float* ad2 = (const float*)d_in[11];
  float* out = (float*)d_out;
  float* ws = (float*)d_ws;

  float* hmat = ws + OFF_HMAT;
  float* svec = ws + OFF_SVEC;
  float* hp   = ws + OFF_HP;
  float* gu   = ws + OFF_GU;
  float* gd   = ws + OFF_GD;
  _Float16* h0T = (_Float16*)(ws + OFF_H0T);

  k_xw<<<dim3(NN / 128, 4, NDIM), 256, 0, stream>>>(X, Wp, Wsm, Wu, Wd, hmat, h0T);
  k_svec<<<dim3(NN / 4, 4, NDIM), 256, 0, stream>>>(hmat, au1, au2, ad1, ad2, svec);
  k_lgemm<<<dim3(NN / 128, 4, NDIM), 256, 0, stream>>>(L, h0T, hp);
  k_gat<<<dim3(NN / 4, 2, NDIM), 256, 0, stream>>>(Lu, Ldn, hmat, svec, gu, gd);
  k_combine<<<1024, 256, 0, stream>>>(hmat, hp, gu, gd, out);
}

// Round 3
// 128.910 us; speedup vs baseline: 2.9091x; 1.0575x over previous
//
#include <hip/hip_runtime.h>
#include <hip/hip_bf16.h>

#define NN 4096
#define FD 128
#define NDIM 2
#define CAP 256

// ---------- workspace layout (float offsets) ----------
// hmat [2][3][4096][128] fp32 : q=0 X@Ws (h_s), q=1 X@Wu, q=2 X@Wd
// svec [2][4][4096]           : v=0 s1u, 1 s2u, 2 s1d, 3 s2d
// hp   [2][4][4096][128] fp32 : split-K partials of L@h0
// gu,gd [2][4096][128]
// h0T  [2][128][4096] f16     : (X@Wp) transposed, f16 (B operand of L-GEMM)
#define OFF_HMAT 0
#define OFF_SVEC 3145728
#define OFF_HP   3178496
#define OFF_GU   7372800
#define OFF_GD   8421376
#define OFF_H0T  9469952

typedef _Float16 f16x8 __attribute__((ext_vector_type(8)));
typedef float f32x4 __attribute__((ext_vector_type(4)));

union P4 { _Float16 h[4]; int2 i2; };

__device__ __forceinline__ float f4get(const float4& v, int j) {
    return j == 0 ? v.x : j == 1 ? v.y : j == 2 ? v.z : v.w;
}

// ---------------- K1: MFMA f16 GEMM  h = X @ W_p, tile 128x128, K=128 ----------------
__global__ __launch_bounds__(256) void k_xw(
    const float* __restrict__ X, const float* __restrict__ Wp,
    const float* __restrict__ Wsm, const float* __restrict__ Wu,
    const float* __restrict__ Wd, float* __restrict__ hmat,
    _Float16* __restrict__ h0T) {
  int d = blockIdx.z, p = blockIdx.y;
  int r0 = blockIdx.x * 128;
  const float* W = (p == 0 ? Wp : p == 1 ? Wsm : p == 2 ? Wu : Wd) + (size_t)d * FD * FD;
  const float* Xd = X + ((size_t)d * NN + r0) * FD;
  __shared__ int4 As4[2048];  // 32 KB: A[128 rows][128 k] f16, XOR-swizzled
  __shared__ int4 Bs4[2048];  // 32 KB: Bt[128 n][128 k] f16, XOR-swizzled
  char* As = (char*)As4; char* Bs = (char*)Bs4;
  int t = threadIdx.x;

#pragma unroll 4
  for (int u = 0; u < 16; u++) {
    int id = t + u * 256;
    int row = id >> 5, k4 = (id & 31) * 4;
    float4 v = *(const float4*)(Xd + (size_t)row * FD + k4);
    P4 pk;
    pk.h[0] = (_Float16)v.x; pk.h[1] = (_Float16)v.y;
    pk.h[2] = (_Float16)v.z; pk.h[3] = (_Float16)v.w;
    int off = (row * 256 + k4 * 2) ^ ((row & 7) << 4);
    *(int2*)(As + off) = pk.i2;
  }
#pragma unroll 4
  for (int u = 0; u < 16; u++) {
    int id = t + u * 256;
    int k = id >> 5, n4 = (id & 31) * 4;
    float4 v = *(const float4*)(W + (size_t)k * FD + n4);
#pragma unroll
    for (int j = 0; j < 4; j++) {
      int n = n4 + j;
      int off = (n * 256 + k * 2) ^ ((n & 7) << 4);
      *(_Float16*)(Bs + off) = (_Float16)f4get(v, j);
    }
  }
  __syncthreads();

  int w = t >> 6, l = t & 63;
  int lr = l & 15, lkb = (l >> 4) * 16;
  f32x4 acc[2][8] = {};
#pragma unroll
  for (int kb = 0; kb < 4; kb++) {
    f16x8 a[2], b[8];
#pragma unroll
    for (int m = 0; m < 2; m++) {
      int row = w * 32 + m * 16 + lr;
      int off = (row * 256 + kb * 64 + lkb) ^ ((row & 7) << 4);
      a[m] = *(const f16x8*)(As + off);
    }
#pragma unroll
    for (int n = 0; n < 8; n++) {
      int rn = n * 16 + lr;
      int off = (rn * 256 + kb * 64 + lkb) ^ ((rn & 7) << 4);
      b[n] = *(const f16x8*)(Bs + off);
    }
#pragma unroll
    for (int m = 0; m < 2; m++)
#pragma unroll
      for (int n = 0; n < 8; n++)
        acc[m][n] = __builtin_amdgcn_mfma_f32_16x16x32_f16(a[m], b[n], acc[m][n], 0, 0, 0);
  }

  if (p == 0) {
    _Float16* hT = h0T + (size_t)d * FD * NN;
#pragma unroll
    for (int m = 0; m < 2; m++)
#pragma unroll
      for (int n = 0; n < 8; n++) {
        int col = n * 16 + lr;
        int grow = r0 + w * 32 + m * 16 + (l >> 4) * 4;
        P4 pk;
#pragma unroll
        for (int r = 0; r < 4; r++) pk.h[r] = (_Float16)acc[m][n][r];
        *(int2*)(hT + (size_t)col * NN + grow) = pk.i2;
      }
  } else {
    float* o = hmat + ((size_t)(d * 3 + p - 1) * NN + r0) * FD;
#pragma unroll
    for (int m = 0; m < 2; m++)
#pragma unroll
      for (int n = 0; n < 8; n++)
#pragma unroll
        for (int r = 0; r < 4; r++)
          o[(size_t)(w * 32 + m * 16 + (l >> 4) * 4 + r) * FD + n * 16 + lr] = acc[m][n][r];
  }
}

// ---------------- K1b: svec = h @ a ----------------
__global__ __launch_bounds__(256) void k_svec(
    const float* __restrict__ hmat, const float* __restrict__ au1,
    const float* __restrict__ au2, const float* __restrict__ ad1,
    const float* __restrict__ ad2, float* __restrict__ svec) {
  int v = blockIdx.y, d = blockIdx.z;
  int w = threadIdx.x >> 6, lane = threadIdx.x & 63;
  int i = blockIdx.x * 4 + w;
  const float* a = (v == 0 ? au1 : v == 1 ? au2 : v == 2 ? ad1 : ad2) + (size_t)d * FD;
  const float* h = hmat + ((size_t)(d * 3 + 1 + (v >> 1)) * NN + i) * FD;
  float x = h[lane] * a[lane] + h[64 + lane] * a[64 + lane];
#pragma unroll
  for (int o = 1; o < 64; o <<= 1) x += __shfl_xor(x, o);
  if (lane == 0) svec[(size_t)(d * 4 + v) * NN + i] = x;
}

// ---------------- K2: MFMA f16 GEMM  hp[d][ks] = L[d][:,slice] @ h0[slice,:]
//                  BM=64, 512 blocks = 2 blocks/CU for stage/MFMA overlap ----
__global__ __launch_bounds__(256) void k_lgemm(
    const float* __restrict__ L, const _Float16* __restrict__ h0T,
    float* __restrict__ hp) {
  int d = blockIdx.z, ks = blockIdx.y;
  int r0 = blockIdx.x * 64;
  const float* Lr = L + (size_t)d * NN * NN;
  const _Float16* hT = h0T + (size_t)d * FD * NN;
  __shared__ int4 As4[512];   //  8 KB: A[64 rows][64 k] f16, XOR-swizzled
  __shared__ int4 Bs4[1024];  // 16 KB: Bt[128 n][64 k] f16, XOR-swizzled
  char* As = (char*)As4; char* Bs = (char*)Bs4;
  int t = threadIdx.x;
  int w = t >> 6, l = t & 63;
  int lr = l & 15, lkb = (l >> 4) * 16;
  f32x4 acc[8] = {};
  int kbeg = ks * 1024;
  for (int kk = kbeg; kk < kbeg + 1024; kk += 64) {
    // stage A: L tile 64x64 fp32 -> f16 (4 float4/thread)
#pragma unroll
    for (int u = 0; u < 4; u++) {
      int id = t + u * 256;
      int row = id >> 4, k4 = (id & 15) * 4;
      float4 v = *(const float4*)(Lr + (size_t)(r0 + row) * NN + kk + k4);
      P4 pk;
      pk.h[0] = (_Float16)v.x; pk.h[1] = (_Float16)v.y;
      pk.h[2] = (_Float16)v.z; pk.h[3] = (_Float16)v.w;
      int off = (row * 128 + k4 * 2) ^ ((row & 7) << 4);
      *(int2*)(As + off) = pk.i2;
    }
    // stage B: h0T [n][k] f16, 4 x 16B per thread
#pragma unroll
    for (int u = 0; u < 4; u++) {
      int id = t + u * 256;
      int n = id >> 3, k8 = (id & 7) * 8;
      int4 v = *(const int4*)(hT + (size_t)n * NN + kk + k8);
      int off = (n * 128 + k8 * 2) ^ ((n & 7) << 4);
      *(int4*)(Bs + off) = v;
    }
    __syncthreads();
#pragma unroll
    for (int kb = 0; kb < 2; kb++) {
      int row = w * 16 + lr;
      int offA = (row * 128 + kb * 64 + lkb) ^ ((row & 7) << 4);
      f16x8 a = *(const f16x8*)(As + offA);
      f16x8 b[8];
#pragma unroll
      for (int n = 0; n < 8; n++) {
        int rn = n * 16 + lr;
        int off = (rn * 128 + kb * 64 + lkb) ^ ((rn & 7) << 4);
        b[n] = *(const f16x8*)(Bs + off);
      }
#pragma unroll
      for (int n = 0; n < 8; n++)
        acc[n] = __builtin_amdgcn_mfma_f32_16x16x32_f16(a, b[n], acc[n], 0, 0, 0);
    }
    __syncthreads();
  }
  float* o = hp + ((size_t)(d * 4 + ks) * NN + r0) * FD;
#pragma unroll
  for (int n = 0; n < 8; n++)
#pragma unroll
    for (int r = 0; r < 4; r++)
      o[(size_t)(w * 16 + (l >> 4) * 4 + r) * FD + n * 16 + lr] = acc[n][r];
}

// ---------------- K3: GAT (sparse softmax over 0/1 adjacency) ----------------
__global__ __launch_bounds__(256) void k_gat(
    const float* __restrict__ Lu, const float* __restrict__ Ldn,
    const float* __restrict__ hmat, const float* __restrict__ svec,
    float* __restrict__ gu, float* __restrict__ gd) {
  int d = blockIdx.z, a = blockIdx.y;
  int w = threadIdx.x >> 6, lane = threadIdx.x & 63;
  int i = blockIdx.x * 4 + w;
  const float* Arow = (a ? Ldn : Lu) + ((size_t)d * NN + i) * (size_t)NN;
  const float* h = hmat + (size_t)(d * 3 + 1 + a) * NN * FD;
  const float* s1 = svec + (size_t)(d * 4 + 2 * a) * NN;
  const float* s2 = svec + (size_t)(d * 4 + 2 * a + 1) * NN;
  float* g = (a ? gd : gu) + ((size_t)d * NN + i) * FD;

  __shared__ int ej[4][CAP];
  __shared__ float wt[4][CAP];
  int cnt = 0;
  // scan: 4 loads (4 KB/wave) in flight per iteration, then ballot-compact
  for (int base = 0; base < NN; base += 1024) {
    float4 v[4];
#pragma unroll
    for (int j = 0; j < 4; j++)
      v[j] = *(const float4*)(Arow + base + j * 256 + lane * 4);
#pragma unroll
    for (int j = 0; j < 4; j++) {
#pragma unroll
      for (int q = 0; q < 4; q++) {
        float vv = f4get(v[j], q);
        unsigned long long m = __ballot(vv == 1.0f);
        if (m) {
          if (vv == 1.0f) {
            int pos = cnt + __popcll(m & ((1ull << lane) - 1ull));
            if (pos < CAP) ej[w][pos] = base + j * 256 + lane * 4 + q;
          }
          cnt += __popcll(m);
        }
      }
    }
  }
  cnt = min(cnt, CAP);
  float s1i = s1[i];
  float mx = -1e30f;
  for (int e0 = 0; e0 < cnt; e0 += 64) {
    int e = e0 + lane;
    float sc = -1e30f;
    if (e < cnt) {
      int j = ej[w][e];
      float x = s1i + s2[j];
      sc = x > 0.0f ? x : 0.01f * x;
      wt[w][e] = sc;
    }
    mx = fmaxf(mx, sc);
  }
#pragma unroll
  for (int o = 1; o < 64; o <<= 1) mx = fmaxf(mx, __shfl_xor(mx, o));
  float sum = 0.0f;
  for (int e0 = 0; e0 < cnt; e0 += 64) {
    int e = e0 + lane;
    float pv = 0.0f;
    if (e < cnt) {
      pv = expf(wt[w][e] - mx);
      wt[w][e] = pv;
    }
    sum += pv;
  }
#pragma unroll
  for (int o = 1; o < 64; o <<= 1) sum += __shfl_xor(sum, o);
  float inv = (cnt > 0) ? 1.0f / sum : 0.0f;
  float acc0 = 0.0f, acc1 = 0.0f;
  int e = 0;
  // gather: 4 edges (8 independent 256B loads) in flight per iteration
  for (; e + 4 <= cnt; e += 4) {
    const float* r0 = h + (size_t)ej[w][e + 0] * FD;
    const float* r1 = h + (size_t)ej[w][e + 1] * FD;
    const float* r2 = h + (size_t)ej[w][e + 2] * FD;
    const float* r3 = h + (size_t)ej[w][e + 3] * FD;
    float w0 = wt[w][e + 0] * inv, w1 = wt[w][e + 1] * inv;
    float w2 = wt[w][e + 2] * inv, w3 = wt[w][e + 3] * inv;
    float a0 = r0[lane], b0 = r0[64 + lane];
    float a1 = r1[lane], b1 = r1[64 + lane];
    float a2 = r2[lane], b2 = r2[64 + lane];
    float a3 = r3[lane], b3 = r3[64 + lane];
    acc0 += w0 * a0 + w1 * a1 + w2 * a2 + w3 * a3;
    acc1 += w0 * b0 + w1 * b1 + w2 * b2 + w3 * b3;
  }
  for (; e < cnt; e++) {
    float wg = wt[w][e] * inv;
    const float* hr = h + (size_t)ej[w][e] * FD;
    acc0 += wg * hr[lane];
    acc1 += wg * hr[64 + lane];
  }
  g[lane] = acc0;
  g[64 + lane] = acc1;
}

// ---------------- K4: combine with tanh ----------------
__global__ __launch_bounds__(256) void k_combine(
    const float* __restrict__ hmat, const float* __restrict__ hp,
    const float* __restrict__ gu, const float* __restrict__ gd,
    float* __restrict__ out) {
  const size_t tot4 = (size_t)NDIM * NN * FD / 4;
  for (size_t i4 = (size_t)blockIdx.x * blockDim.x + threadIdx.x; i4 < tot4;
       i4 += (size_t)gridDim.x * blockDim.x) {
    size_t i = i4 * 4;
    int d = (int)(i >> 19);
    size_t rem = i & 524287;
    float4 hs = *(const float4*)(hmat + ((size_t)(d * 3) << 19) + rem);
    float4 p0 = *(const float4*)(hp + ((size_t)(d * 4 + 0) << 19) + rem);
    float4 p1 = *(const float4*)(hp + ((size_t)(d * 4 + 1) << 19) + rem);
    float4 p2 = *(const float4*)(hp + ((size_t)(d * 4 + 2) << 19) + rem);
    float4 p3 = *(const float4*)(hp + ((size_t)(d * 4 + 3) << 19) + rem);
    float4 u = *(const float4*)(gu + ((size_t)d << 19) + rem);
    float4 dd = *(const float4*)(gd + ((size_t)d << 19) + rem);
    float4 o;
    o.x = tanhf(hs.x) + tanhf(u.x) + tanhf(dd.x) + tanhf(p0.x + p1.x + p2.x + p3.x);
    o.y = tanhf(hs.y) + tanhf(u.y) + tanhf(dd.y) + tanhf(p0.y + p1.y + p2.y + p3.y);
    o.z = tanhf(hs.z) + tanhf(u.z) + tanhf(dd.z) + tanhf(p0.z + p1.z + p2.z + p3.z);
    o.w = tanhf(hs.w) + tanhf(u.w) + tanhf(dd.w) + tanhf(p0.w + p1.w + p2.w + p3.w);
    *(float4*)(out + i) = o;
  }
}

extern "C" void kernel_launch(void* const* d_in, const int* in_sizes, int n_in,
                              void* d_out, int out_size, void* d_ws, size_t ws_size,
                              hipStream_t stream) {
  const float* X   = (const float*)d_in[0];
  const float* L   = (const float*)d_in[1];
  const float* Lu  = (const float*)d_in[2];
  const float* Ldn = (const float*)d_in[3];
  const float* Wp  = (const float*)d_in[4];
  const float* Wsm = (const float*)d_in[5];
  const float* Wu  = (const float*)d_in[6];
  const float* au1 = (const float*)d_in[7];
  const float* au2 = (const float*)d_in[8];
  const float* Wd  = (const float*)d_in[9];
  const float* ad1 = (const float*)d_in[10];
  const float* ad2 = (const float*)d_in[11];
  float* out = (float*)d_out;
  float* ws = (float*)d_ws;

  float* hmat = ws + OFF_HMAT;
  float* svec = ws + OFF_SVEC;
  float* hp   = ws + OFF_HP;
  float* gu   = ws + OFF_GU;
  float* gd   = ws + OFF_GD;
  _Float16* h0T = (_Float16*)(ws + OFF_H0T);

  k_xw<<<dim3(NN / 128, 4, NDIM), 256, 0, stream>>>(X, Wp, Wsm, Wu, Wd, hmat, h0T);
  k_svec<<<dim3(NN / 4, 4, NDIM), 256, 0, stream>>>(hmat, au1, au2, ad1, ad2, svec);
  k_lgemm<<<dim3(NN / 64, 4, NDIM), 256, 0, stream>>>(L, h0T, hp);
  k_gat<<<dim3(NN / 4, 2, NDIM), 256, 0, stream>>>(Lu, Ldn, hmat, svec, gu, gd);
  k_combine<<<1024, 256, 0, stream>>>(hmat, hp, gu, gd, out);
}